// Round 6
// baseline (235.788 us; speedup 1.0000x reference)
//
#include <hip/hip_runtime.h>

#define BATCH 262144

typedef __attribute__((ext_vector_type(8))) short short8;
typedef __attribute__((ext_vector_type(4))) float f32x4;

static __device__ __forceinline__ unsigned cvtpk(float lo, float hi) {
    unsigned r;
    asm("v_cvt_pk_bf16_f32 %0, %1, %2" : "=v"(r) : "v"(lo), "v"(hi));
    return r;
}
static __device__ __forceinline__ short8 pack8(f32x4 a, f32x4 b) {
    union { unsigned u[4]; short8 s; } r;
    r.u[0] = cvtpk(a[0], a[1]); r.u[1] = cvtpk(a[2], a[3]);
    r.u[2] = cvtpk(b[0], b[1]); r.u[3] = cvtpk(b[2], b[3]);
    return r.s;
}
// float -> bf16 bits (RNE) for the weight-prep kernel
static __device__ __forceinline__ unsigned short f2b(float f) {
    unsigned u = __float_as_uint(f);
    return (unsigned short)((u + 0x7fffu + ((u >> 16) & 1u)) >> 16);
}
static __device__ __forceinline__ float sigm(float x) { return 1.0f / (1.0f + __expf(-x)); }
static __device__ __forceinline__ float tanh_f(float x) { return 1.0f - 2.0f / (__expf(2.0f * x) + 1.0f); }

// All LDS buffers are PER-WAVE -> no __syncthreads; lgkmcnt(0) orders ds ops.
#define WAVE_FENCE() asm volatile("s_waitcnt lgkmcnt(0)" ::: "memory")

// XOR swizzle, unpadded rows. [16][64] bf16: 128 B rows. [16][128] bf16: 256 B rows.
static __device__ __forceinline__ int sw128(int row, int cb) { return row * 128 + (cb ^ ((row & 7) << 4)); }
static __device__ __forceinline__ int sw256(int row, int cb) { return row * 256 + (cb ^ ((row & 7) << 4)); }

// bf16 weights in workspace: [0:8192) w1, [8192:12288) w2, [12288:24576) w_ih,
//                            [24576:36864) w_hh, [36864:45056) lp_w1
__global__ void prep_weights(const float* __restrict__ w1, const float* __restrict__ w2,
                             const float* __restrict__ wih, const float* __restrict__ whh,
                             const float* __restrict__ lw1, unsigned short* __restrict__ wsb) {
    int i = blockIdx.x * 256 + threadIdx.x;
    float v;
    if (i < 8192) v = w1[i];
    else if (i < 12288) v = w2[i - 8192];
    else if (i < 24576) v = wih[i - 12288];
    else if (i < 36864) v = whh[i - 24576];
    else if (i < 45056) v = lw1[i - 36864];
    else return;
    wsb[i] = f2b(v);
}

// (256,4): total reg budget 128/wave (incl. AGPR, unified file). R4 proved <=102
// spills; R5 proved unbounded (112+AGPR) halves occupancy. 128 is the sweet spot.
__global__ __launch_bounds__(256, 4) void tgn_kernel(
    const int* __restrict__ pairs, const float* __restrict__ memory,
    const unsigned short* __restrict__ wsb,
    const float* __restrict__ b1, const float* __restrict__ b2,
    const float* __restrict__ bih, const float* __restrict__ bhh,
    const float* __restrict__ lb1, const float* __restrict__ lw2,
    const float* __restrict__ lb2, float* __restrict__ out)
{
    // 4 KB per wave: h1 @0 (2K), msg @2048 (2K); comb [16][128] overlays all 4K.
    __shared__ __align__(16) char scr[4][4096];   // 16 KB/block

    const int tid = threadIdx.x;
    const int w  = tid >> 6;
    const int l  = tid & 63;
    const int lr = l & 15;       // M/N index within fragment
    const int lg = l >> 4;       // k-group / row-group

    const int r0 = (blockIdx.x * 4 + w) * 16;

    char* h1b  = &scr[w][0];
    char* msgb = &scr[w][2048];
    char* comb = &scr[w][0];

    const unsigned short* w1b  = wsb;          // [64][128]
    const unsigned short* w2b  = wsb + 8192;   // [64][64]
    const unsigned short* wihb = wsb + 12288;  // [192][64]
    const unsigned short* whhb = wsb + 24576;  // [192][64]
    const unsigned short* lw1b = wsb + 36864;  // [64][128]

    const f32x4 z4 = {0.0f, 0.0f, 0.0f, 0.0f};

    // ---- stage 0: gather DIRECTLY into A-fragments (no LDS round-trip) ----
    // A-frag layout for 16x16x32: lane(lr,lg) holds row lr, k = kt*32 + lg*8 .. +7.
    {
    }
    const long i1 = pairs[(r0 + lr) * 2 + 0];
    const long i2 = pairs[(r0 + lr) * 2 + 1];
    const float* m1 = memory + i1 * 64;
    const float* m2 = memory + i2 * 64;
    short8 a1[2], a2[2];
    {
        f32x4 x0 = *(const f32x4*)(m1 + lg * 8);
        f32x4 x1 = *(const f32x4*)(m1 + lg * 8 + 4);
        f32x4 x2 = *(const f32x4*)(m1 + 32 + lg * 8);
        f32x4 x3 = *(const f32x4*)(m1 + 32 + lg * 8 + 4);
        a1[0] = pack8(x0, x1); a1[1] = pack8(x2, x3);
        f32x4 y0 = *(const f32x4*)(m2 + lg * 8);
        f32x4 y1 = *(const f32x4*)(m2 + lg * 8 + 4);
        f32x4 y2 = *(const f32x4*)(m2 + 32 + lg * 8);
        f32x4 y3 = *(const f32x4*)(m2 + 32 + lg * 8 + 4);
        a2[0] = pack8(y0, y1); a2[1] = pack8(y2, y3);
    }

    // ---- stage 1: H1 = relu(X @ w1^T + b1), X = [n1|n2] (16x128) ----
    f32x4 acc[4];
#pragma unroll
    for (int nt = 0; nt < 4; ++nt) acc[nt] = z4;
#pragma unroll
    for (int kt = 0; kt < 4; ++kt) {
        short8 a = (kt == 0) ? a1[0] : (kt == 1) ? a1[1] : (kt == 2) ? a2[0] : a2[1];
#pragma unroll
        for (int nt = 0; nt < 4; ++nt) {
            short8 b = *(const short8*)(w1b + (nt * 16 + lr) * 128 + kt * 32 + lg * 8);
            acc[nt] = __builtin_amdgcn_mfma_f32_16x16x32_bf16(a, b, acc[nt], 0, 0, 0);
        }
    }
#pragma unroll
    for (int nt = 0; nt < 4; ++nt) {
        float bv = b1[nt * 16 + lr];
        unsigned p01 = cvtpk(fmaxf(acc[nt][0] + bv, 0.0f), fmaxf(acc[nt][1] + bv, 0.0f));
        unsigned p23 = cvtpk(fmaxf(acc[nt][2] + bv, 0.0f), fmaxf(acc[nt][3] + bv, 0.0f));
        int cb = nt * 32 + lr * 2;
        *(unsigned short*)(h1b + sw128(lg * 4 + 0, cb)) = (unsigned short)p01;
        *(unsigned short*)(h1b + sw128(lg * 4 + 1, cb)) = (unsigned short)(p01 >> 16);
        *(unsigned short*)(h1b + sw128(lg * 4 + 2, cb)) = (unsigned short)p23;
        *(unsigned short*)(h1b + sw128(lg * 4 + 3, cb)) = (unsigned short)(p23 >> 16);
    }
    WAVE_FENCE();

    // ---- stage 2: MSG = H1 @ w2^T + b2 (16x64) ----
#pragma unroll
    for (int nt = 0; nt < 4; ++nt) acc[nt] = z4;
#pragma unroll
    for (int kt = 0; kt < 2; ++kt) {
        short8 a = *(const short8*)(h1b + sw128(lr, kt * 64 + lg * 16));
#pragma unroll
        for (int nt = 0; nt < 4; ++nt) {
            short8 b = *(const short8*)(w2b + (nt * 16 + lr) * 64 + kt * 32 + lg * 8);
            acc[nt] = __builtin_amdgcn_mfma_f32_16x16x32_bf16(a, b, acc[nt], 0, 0, 0);
        }
    }
#pragma unroll
    for (int nt = 0; nt < 4; ++nt) {
        float bv = b2[nt * 16 + lr];
        unsigned p01 = cvtpk(acc[nt][0] + bv, acc[nt][1] + bv);
        unsigned p23 = cvtpk(acc[nt][2] + bv, acc[nt][3] + bv);
        int cb = nt * 32 + lr * 2;
        *(unsigned short*)(msgb + sw128(lg * 4 + 0, cb)) = (unsigned short)p01;
        *(unsigned short*)(msgb + sw128(lg * 4 + 1, cb)) = (unsigned short)(p01 >> 16);
        *(unsigned short*)(msgb + sw128(lg * 4 + 2, cb)) = (unsigned short)p23;
        *(unsigned short*)(msgb + sw128(lg * 4 + 3, cb)) = (unsigned short)(p23 >> 16);
    }
    WAVE_FENCE();

    // pair indices for the GRU rows this thread owns (C-layout rows lg*4+r)
    long i1g[4], i2g[4];
#pragma unroll
    for (int r = 0; r < 4; ++r) {
        i1g[r] = pairs[(r0 + lg * 4 + r) * 2 + 0];
        i2g[r] = pairs[(r0 + lg * 4 + r) * 2 + 1];
    }

    // ---- stage 3+4 fused: per column-block nt, 9 gate tiles then GRU ----
    short8 am[2];
    am[0] = *(const short8*)(msgb + sw128(lr, lg * 16));
    am[1] = *(const short8*)(msgb + sw128(lr, 64 + lg * 16));
#pragma unroll
    for (int nt = 0; nt < 4; ++nt) {
        f32x4 gir = z4, giz = z4, gin = z4;
        f32x4 g1r = z4, g1z = z4, g1n = z4;
        f32x4 g2r = z4, g2z = z4, g2n = z4;
#pragma unroll
        for (int kt = 0; kt < 2; ++kt) {
            int ko = kt * 32 + lg * 8;
            short8 bir = *(const short8*)(wihb + ((0 + nt) * 16 + lr) * 64 + ko);
            short8 biz = *(const short8*)(wihb + ((4 + nt) * 16 + lr) * 64 + ko);
            short8 bin = *(const short8*)(wihb + ((8 + nt) * 16 + lr) * 64 + ko);
            short8 bhr = *(const short8*)(whhb + ((0 + nt) * 16 + lr) * 64 + ko);
            short8 bhz = *(const short8*)(whhb + ((4 + nt) * 16 + lr) * 64 + ko);
            short8 bhn = *(const short8*)(whhb + ((8 + nt) * 16 + lr) * 64 + ko);
            gir = __builtin_amdgcn_mfma_f32_16x16x32_bf16(am[kt], bir, gir, 0, 0, 0);
            giz = __builtin_amdgcn_mfma_f32_16x16x32_bf16(am[kt], biz, giz, 0, 0, 0);
            gin = __builtin_amdgcn_mfma_f32_16x16x32_bf16(am[kt], bin, gin, 0, 0, 0);
            g1r = __builtin_amdgcn_mfma_f32_16x16x32_bf16(a1[kt], bhr, g1r, 0, 0, 0);
            g1z = __builtin_amdgcn_mfma_f32_16x16x32_bf16(a1[kt], bhz, g1z, 0, 0, 0);
            g1n = __builtin_amdgcn_mfma_f32_16x16x32_bf16(a1[kt], bhn, g1n, 0, 0, 0);
            g2r = __builtin_amdgcn_mfma_f32_16x16x32_bf16(a2[kt], bhr, g2r, 0, 0, 0);
            g2z = __builtin_amdgcn_mfma_f32_16x16x32_bf16(a2[kt], bhz, g2z, 0, 0, 0);
            g2n = __builtin_amdgcn_mfma_f32_16x16x32_bf16(a2[kt], bhn, g2n, 0, 0, 0);
        }
        int j = nt * 16 + lr;
        float bir_ = bih[j], biz_ = bih[64 + j], bin_ = bih[128 + j];
        float bhr_ = bhh[j], bhz_ = bhh[64 + j], bhn_ = bhh[128 + j];
        float o1[4], o2[4];
#pragma unroll
        for (int r = 0; r < 4; ++r) {
            float i_r = gir[r] + bir_;
            float i_z = giz[r] + biz_;
            float i_n = gin[r] + bin_;
            // node 1 (h read from global f32 — rows are L1-hot from stage 0)
            float rg = sigm(i_r + g1r[r] + bhr_);
            float zg = sigm(i_z + g1z[r] + bhz_);
            float ng = tanh_f(i_n + rg * (g1n[r] + bhn_));
            float h  = memory[i1g[r] * 64 + j];
            o1[r] = (1.0f - zg) * ng + zg * h;
            // node 2
            rg = sigm(i_r + g2r[r] + bhr_);
            zg = sigm(i_z + g2z[r] + bhz_);
            ng = tanh_f(i_n + rg * (g2n[r] + bhn_));
            h  = memory[i2g[r] * 64 + j];
            o2[r] = (1.0f - zg) * ng + zg * h;
        }
        unsigned q01 = cvtpk(o1[0], o1[1]), q23 = cvtpk(o1[2], o1[3]);
        unsigned s01 = cvtpk(o2[0], o2[1]), s23 = cvtpk(o2[2], o2[3]);
        *(unsigned short*)(comb + sw256(lg * 4 + 0, j * 2)) = (unsigned short)q01;
        *(unsigned short*)(comb + sw256(lg * 4 + 1, j * 2)) = (unsigned short)(q01 >> 16);
        *(unsigned short*)(comb + sw256(lg * 4 + 2, j * 2)) = (unsigned short)q23;
        *(unsigned short*)(comb + sw256(lg * 4 + 3, j * 2)) = (unsigned short)(q23 >> 16);
        *(unsigned short*)(comb + sw256(lg * 4 + 0, 128 + j * 2)) = (unsigned short)s01;
        *(unsigned short*)(comb + sw256(lg * 4 + 1, 128 + j * 2)) = (unsigned short)(s01 >> 16);
        *(unsigned short*)(comb + sw256(lg * 4 + 2, 128 + j * 2)) = (unsigned short)s23;
        *(unsigned short*)(comb + sw256(lg * 4 + 3, 128 + j * 2)) = (unsigned short)(s23 >> 16);
    }
    WAVE_FENCE();

    // ---- stage 5: H = relu(COMB @ lp_w1^T + lb1) (16x64) ----
    f32x4 acc5[4];
#pragma unroll
    for (int nt = 0; nt < 4; ++nt) acc5[nt] = z4;
#pragma unroll
    for (int kt = 0; kt < 4; ++kt) {
        short8 a = *(const short8*)(comb + sw256(lr, kt * 64 + lg * 16));
#pragma unroll
        for (int nt = 0; nt < 4; ++nt) {
            short8 b = *(const short8*)(lw1b + (nt * 16 + lr) * 128 + kt * 32 + lg * 8);
            acc5[nt] = __builtin_amdgcn_mfma_f32_16x16x32_bf16(a, b, acc5[nt], 0, 0, 0);
        }
    }

    // ---- stage 6: out = sigmoid(H @ lp_w2^T + lb2), reduce over 64 cols ----
    float part[4] = {0.0f, 0.0f, 0.0f, 0.0f};
#pragma unroll
    for (int nt = 0; nt < 4; ++nt) {
        float w2v = lw2[nt * 16 + lr];
        float bv  = lb1[nt * 16 + lr];
#pragma unroll
        for (int r = 0; r < 4; ++r)
            part[r] += fmaxf(acc5[nt][r] + bv, 0.0f) * w2v;
    }
    float lb2v = lb2[0];
#pragma unroll
    for (int r = 0; r < 4; ++r) {
        float p = part[r];
        p += __shfl_xor(p, 1);
        p += __shfl_xor(p, 2);
        p += __shfl_xor(p, 4);
        p += __shfl_xor(p, 8);
        if (lr == 0) out[r0 + lg * 4 + r] = sigm(p + lb2v);
    }
}

extern "C" void kernel_launch(void* const* d_in, const int* in_sizes, int n_in,
                              void* d_out, int out_size, void* d_ws, size_t ws_size,
                              hipStream_t stream) {
    const int*   pairs  = (const int*)d_in[0];
    const float* memory = (const float*)d_in[1];
    const float* w1  = (const float*)d_in[2];
    const float* b1  = (const float*)d_in[3];
    const float* w2  = (const float*)d_in[4];
    const float* b2  = (const float*)d_in[5];
    const float* wih = (const float*)d_in[6];
    const float* whh = (const float*)d_in[7];
    const float* bih = (const float*)d_in[8];
    const float* bhh = (const float*)d_in[9];
    const float* lw1 = (const float*)d_in[10];
    const float* lb1 = (const float*)d_in[11];
    const float* lw2 = (const float*)d_in[12];
    const float* lb2 = (const float*)d_in[13];
    unsigned short* wsb = (unsigned short*)d_ws;

    prep_weights<<<176, 256, 0, stream>>>(w1, w2, wih, whh, lw1, wsb);
    tgn_kernel<<<BATCH / 64, 256, 0, stream>>>(pairs, memory, wsb, b1, b2, bih, bhh,
                                               lb1, lw2, lb2, (float*)d_out);
}

// Round 7
// 191.012 us; speedup vs baseline: 1.2344x; 1.2344x over previous
//
#include <hip/hip_runtime.h>

#define BATCH 262144

typedef __attribute__((ext_vector_type(8))) short short8;
typedef __attribute__((ext_vector_type(4))) float f32x4;

static __device__ __forceinline__ unsigned cvtpk(float lo, float hi) {
    unsigned r;
    asm("v_cvt_pk_bf16_f32 %0, %1, %2" : "=v"(r) : "v"(lo), "v"(hi));
    return r;
}
static __device__ __forceinline__ short8 pack8(f32x4 a, f32x4 b) {
    union { unsigned u[4]; short8 s; } r;
    r.u[0] = cvtpk(a[0], a[1]); r.u[1] = cvtpk(a[2], a[3]);
    r.u[2] = cvtpk(b[0], b[1]); r.u[3] = cvtpk(b[2], b[3]);
    return r.s;
}
// float -> bf16 bits (RNE) for the weight-prep kernel
static __device__ __forceinline__ unsigned short f2b(float f) {
    unsigned u = __float_as_uint(f);
    return (unsigned short)((u + 0x7fffu + ((u >> 16) & 1u)) >> 16);
}
static __device__ __forceinline__ float b2f(short s) {
    return __uint_as_float(((unsigned)(unsigned short)s) << 16);
}
static __device__ __forceinline__ float sigm(float x) { return 1.0f / (1.0f + __expf(-x)); }
static __device__ __forceinline__ float tanh_f(float x) { return 1.0f - 2.0f / (__expf(2.0f * x) + 1.0f); }

// All LDS buffers are PER-WAVE -> no __syncthreads; lgkmcnt(0) orders ds ops.
#define WAVE_FENCE() asm volatile("s_waitcnt lgkmcnt(0)" ::: "memory")

// bf16 weights in workspace: [0:8192) w1, [8192:12288) w2, [12288:24576) w_ih,
//                            [24576:36864) w_hh, [36864:45056) lp_w1
__global__ void prep_weights(const float* __restrict__ w1, const float* __restrict__ w2,
                             const float* __restrict__ wih, const float* __restrict__ whh,
                             const float* __restrict__ lw1, unsigned short* __restrict__ wsb) {
    int i = blockIdx.x * 256 + threadIdx.x;
    float v;
    if (i < 8192) v = w1[i];
    else if (i < 12288) v = w2[i - 8192];
    else if (i < 24576) v = wih[i - 12288];
    else if (i < 36864) v = whh[i - 24576];
    else if (i < 45056) v = lw1[i - 36864];
    else return;
    wsb[i] = f2b(v);
}

#define LDB 72    // bf16 LDS row stride: 144 B rows (9*16 -> every row 16B-aligned)
#define LDC 136   // comb row stride: 272 B rows (17*16)

// (256,4): 128 regs/wave total (VGPR+AGPR unified) — R4/R6 proved lower spills,
// R5 proved higher halves occupancy for no gain.
__global__ __launch_bounds__(256, 4) void tgn_kernel(
    const int* __restrict__ pairs, const float* __restrict__ memory,
    const unsigned short* __restrict__ wsb,
    const float* __restrict__ b1, const float* __restrict__ b2,
    const float* __restrict__ bih, const float* __restrict__ bhh,
    const float* __restrict__ lb1, const float* __restrict__ lw2,
    const float* __restrict__ lb2, float* __restrict__ out)
{
    __shared__ __align__(16) short nmem[4][2][16 * LDB];  // 18432 B: n1/n2 bf16 (GRU h source)
    __shared__ __align__(16) short scr[4][2304];          // 18432 B: h1b@0, msgb@1152; comb overlays

    const int tid = threadIdx.x;
    const int w  = tid >> 6;
    const int l  = tid & 63;
    const int lr = l & 15;       // M/N index within fragment
    const int lg = l >> 4;       // k-group / row-group

    const int r0 = (blockIdx.x * 4 + w) * 16;

    short* n1b  = &nmem[w][0][0];
    short* n2b  = &nmem[w][1][0];
    short* h1b  = &scr[w][0];
    short* msgb = &scr[w][1152];
    short* comb = &scr[w][0];

    const unsigned short* w1b  = wsb;          // [64][128]
    const unsigned short* w2b  = wsb + 8192;   // [64][64]
    const unsigned short* wihb = wsb + 12288;  // [192][64]
    const unsigned short* whhb = wsb + 24576;  // [192][64]
    const unsigned short* lw1b = wsb + 36864;  // [64][128]

    const f32x4 z4 = {0.0f, 0.0f, 0.0f, 0.0f};

    // ---- stage 0: gather DIRECTLY into A-fragments, mirror to LDS for GRU h ----
    // A-frag (16x16x32): lane(lr,lg) holds row lr, k = kt*32 + lg*8 .. +7.
    short8 a1[2], a2[2];
    {
        const long i1 = pairs[(r0 + lr) * 2 + 0];
        const long i2 = pairs[(r0 + lr) * 2 + 1];
        const float* m1 = memory + i1 * 64;
        const float* m2 = memory + i2 * 64;
        f32x4 x0 = *(const f32x4*)(m1 + lg * 8);
        f32x4 x1 = *(const f32x4*)(m1 + lg * 8 + 4);
        f32x4 x2 = *(const f32x4*)(m1 + 32 + lg * 8);
        f32x4 x3 = *(const f32x4*)(m1 + 32 + lg * 8 + 4);
        a1[0] = pack8(x0, x1); a1[1] = pack8(x2, x3);
        f32x4 y0 = *(const f32x4*)(m2 + lg * 8);
        f32x4 y1 = *(const f32x4*)(m2 + lg * 8 + 4);
        f32x4 y2 = *(const f32x4*)(m2 + 32 + lg * 8);
        f32x4 y3 = *(const f32x4*)(m2 + 32 + lg * 8 + 4);
        a2[0] = pack8(y0, y1); a2[1] = pack8(y2, y3);
        // mirror to LDS (row lr, cols lg*8..+8 and 32+lg*8..+8) — 16B aligned
        *(short8*)(n1b + lr * LDB + lg * 8)      = a1[0];
        *(short8*)(n1b + lr * LDB + 32 + lg * 8) = a1[1];
        *(short8*)(n2b + lr * LDB + lg * 8)      = a2[0];
        *(short8*)(n2b + lr * LDB + 32 + lg * 8) = a2[1];
    }

    // ---- stage 1: H1 = relu(X @ w1^T + b1), X = [n1|n2] (16x128) ----
    f32x4 acc[4];
#pragma unroll
    for (int nt = 0; nt < 4; ++nt) acc[nt] = z4;
#pragma unroll
    for (int kt = 0; kt < 4; ++kt) {
        short8 a = (kt == 0) ? a1[0] : (kt == 1) ? a1[1] : (kt == 2) ? a2[0] : a2[1];
#pragma unroll
        for (int nt = 0; nt < 4; ++nt) {
            short8 b = *(const short8*)(w1b + (nt * 16 + lr) * 128 + kt * 32 + lg * 8);
            acc[nt] = __builtin_amdgcn_mfma_f32_16x16x32_bf16(a, b, acc[nt], 0, 0, 0);
        }
    }
#pragma unroll
    for (int nt = 0; nt < 4; ++nt) {
        float bv = b1[nt * 16 + lr];
        unsigned p01 = cvtpk(fmaxf(acc[nt][0] + bv, 0.0f), fmaxf(acc[nt][1] + bv, 0.0f));
        unsigned p23 = cvtpk(fmaxf(acc[nt][2] + bv, 0.0f), fmaxf(acc[nt][3] + bv, 0.0f));
        int cb = nt * 16 + lr;
        h1b[(lg * 4 + 0) * LDB + cb] = (short)p01;
        h1b[(lg * 4 + 1) * LDB + cb] = (short)(p01 >> 16);
        h1b[(lg * 4 + 2) * LDB + cb] = (short)p23;
        h1b[(lg * 4 + 3) * LDB + cb] = (short)(p23 >> 16);
    }
    WAVE_FENCE();

    // ---- stage 2: MSG = H1 @ w2^T + b2 (16x64) ----
#pragma unroll
    for (int nt = 0; nt < 4; ++nt) acc[nt] = z4;
#pragma unroll
    for (int kt = 0; kt < 2; ++kt) {
        short8 a = *(const short8*)(h1b + lr * LDB + kt * 32 + lg * 8);
#pragma unroll
        for (int nt = 0; nt < 4; ++nt) {
            short8 b = *(const short8*)(w2b + (nt * 16 + lr) * 64 + kt * 32 + lg * 8);
            acc[nt] = __builtin_amdgcn_mfma_f32_16x16x32_bf16(a, b, acc[nt], 0, 0, 0);
        }
    }
#pragma unroll
    for (int nt = 0; nt < 4; ++nt) {
        float bv = b2[nt * 16 + lr];
        unsigned p01 = cvtpk(acc[nt][0] + bv, acc[nt][1] + bv);
        unsigned p23 = cvtpk(acc[nt][2] + bv, acc[nt][3] + bv);
        int cb = nt * 16 + lr;
        msgb[(lg * 4 + 0) * LDB + cb] = (short)p01;
        msgb[(lg * 4 + 1) * LDB + cb] = (short)(p01 >> 16);
        msgb[(lg * 4 + 2) * LDB + cb] = (short)p23;
        msgb[(lg * 4 + 3) * LDB + cb] = (short)(p23 >> 16);
    }
    WAVE_FENCE();

    // ---- stage 3+4 fused: per column-block nt, 9 gate tiles then GRU ----
    short8 am[2];
    am[0] = *(const short8*)(msgb + lr * LDB + lg * 8);
    am[1] = *(const short8*)(msgb + lr * LDB + 32 + lg * 8);
#pragma unroll
    for (int nt = 0; nt < 4; ++nt) {
        f32x4 gir = z4, giz = z4, gin = z4;
        f32x4 g1r = z4, g1z = z4, g1n = z4;
        f32x4 g2r = z4, g2z = z4, g2n = z4;
#pragma unroll
        for (int kt = 0; kt < 2; ++kt) {
            int ko = kt * 32 + lg * 8;
            short8 bir = *(const short8*)(wihb + ((0 + nt) * 16 + lr) * 64 + ko);
            short8 biz = *(const short8*)(wihb + ((4 + nt) * 16 + lr) * 64 + ko);
            short8 bin = *(const short8*)(wihb + ((8 + nt) * 16 + lr) * 64 + ko);
            short8 bhr = *(const short8*)(whhb + ((0 + nt) * 16 + lr) * 64 + ko);
            short8 bhz = *(const short8*)(whhb + ((4 + nt) * 16 + lr) * 64 + ko);
            short8 bhn = *(const short8*)(whhb + ((8 + nt) * 16 + lr) * 64 + ko);
            gir = __builtin_amdgcn_mfma_f32_16x16x32_bf16(am[kt], bir, gir, 0, 0, 0);
            giz = __builtin_amdgcn_mfma_f32_16x16x32_bf16(am[kt], biz, giz, 0, 0, 0);
            gin = __builtin_amdgcn_mfma_f32_16x16x32_bf16(am[kt], bin, gin, 0, 0, 0);
            g1r = __builtin_amdgcn_mfma_f32_16x16x32_bf16(a1[kt], bhr, g1r, 0, 0, 0);
            g1z = __builtin_amdgcn_mfma_f32_16x16x32_bf16(a1[kt], bhz, g1z, 0, 0, 0);
            g1n = __builtin_amdgcn_mfma_f32_16x16x32_bf16(a1[kt], bhn, g1n, 0, 0, 0);
            g2r = __builtin_amdgcn_mfma_f32_16x16x32_bf16(a2[kt], bhr, g2r, 0, 0, 0);
            g2z = __builtin_amdgcn_mfma_f32_16x16x32_bf16(a2[kt], bhz, g2z, 0, 0, 0);
            g2n = __builtin_amdgcn_mfma_f32_16x16x32_bf16(a2[kt], bhn, g2n, 0, 0, 0);
        }
        int j = nt * 16 + lr;
        float bir_ = bih[j], biz_ = bih[64 + j], bin_ = bih[128 + j];
        float bhr_ = bhh[j], bhz_ = bhh[64 + j], bhn_ = bhh[128 + j];
        float o1[4], o2[4];
#pragma unroll
        for (int r = 0; r < 4; ++r) {
            int row = lg * 4 + r;
            float i_r = gir[r] + bir_;
            float i_z = giz[r] + biz_;
            float i_n = gin[r] + bin_;
            // node 1 (h from LDS bf16 copy — no global re-read)
            float rg = sigm(i_r + g1r[r] + bhr_);
            float zg = sigm(i_z + g1z[r] + bhz_);
            float ng = tanh_f(i_n + rg * (g1n[r] + bhn_));
            float h  = b2f(n1b[row * LDB + j]);
            o1[r] = (1.0f - zg) * ng + zg * h;
            // node 2
            rg = sigm(i_r + g2r[r] + bhr_);
            zg = sigm(i_z + g2z[r] + bhz_);
            ng = tanh_f(i_n + rg * (g2n[r] + bhn_));
            h  = b2f(n2b[row * LDB + j]);
            o2[r] = (1.0f - zg) * ng + zg * h;
        }
        unsigned q01 = cvtpk(o1[0], o1[1]), q23 = cvtpk(o1[2], o1[3]);
        unsigned s01 = cvtpk(o2[0], o2[1]), s23 = cvtpk(o2[2], o2[3]);
        comb[(lg * 4 + 0) * LDC + j] = (short)q01;
        comb[(lg * 4 + 1) * LDC + j] = (short)(q01 >> 16);
        comb[(lg * 4 + 2) * LDC + j] = (short)q23;
        comb[(lg * 4 + 3) * LDC + j] = (short)(q23 >> 16);
        comb[(lg * 4 + 0) * LDC + 64 + j] = (short)s01;
        comb[(lg * 4 + 1) * LDC + 64 + j] = (short)(s01 >> 16);
        comb[(lg * 4 + 2) * LDC + 64 + j] = (short)s23;
        comb[(lg * 4 + 3) * LDC + 64 + j] = (short)(s23 >> 16);
    }
    WAVE_FENCE();

    // ---- stage 5: H = relu(COMB @ lp_w1^T + lb1) (16x64) ----
    f32x4 acc5[4];
#pragma unroll
    for (int nt = 0; nt < 4; ++nt) acc5[nt] = z4;
#pragma unroll
    for (int kt = 0; kt < 4; ++kt) {
        short8 a = *(const short8*)(comb + lr * LDC + kt * 32 + lg * 8);
#pragma unroll
        for (int nt = 0; nt < 4; ++nt) {
            short8 b = *(const short8*)(lw1b + (nt * 16 + lr) * 128 + kt * 32 + lg * 8);
            acc5[nt] = __builtin_amdgcn_mfma_f32_16x16x32_bf16(a, b, acc5[nt], 0, 0, 0);
        }
    }

    // ---- stage 6: out = sigmoid(H @ lp_w2^T + lb2), reduce over 64 cols ----
    float part[4] = {0.0f, 0.0f, 0.0f, 0.0f};
#pragma unroll
    for (int nt = 0; nt < 4; ++nt) {
        float w2v = lw2[nt * 16 + lr];
        float bv  = lb1[nt * 16 + lr];
#pragma unroll
        for (int r = 0; r < 4; ++r)
            part[r] += fmaxf(acc5[nt][r] + bv, 0.0f) * w2v;
    }
    float lb2v = lb2[0];
#pragma unroll
    for (int r = 0; r < 4; ++r) {
        float p = part[r];
        p += __shfl_xor(p, 1);
        p += __shfl_xor(p, 2);
        p += __shfl_xor(p, 4);
        p += __shfl_xor(p, 8);
        if (lr == 0) out[r0 + lg * 4 + r] = sigm(p + lb2v);
    }
}

extern "C" void kernel_launch(void* const* d_in, const int* in_sizes, int n_in,
                              void* d_out, int out_size, void* d_ws, size_t ws_size,
                              hipStream_t stream) {
    const int*   pairs  = (const int*)d_in[0];
    const float* memory = (const float*)d_in[1];
    const float* w1  = (const float*)d_in[2];
    const float* b1  = (const float*)d_in[3];
    const float* w2  = (const float*)d_in[4];
    const float* b2  = (const float*)d_in[5];
    const float* wih = (const float*)d_in[6];
    const float* whh = (const float*)d_in[7];
    const float* bih = (const float*)d_in[8];
    const float* bhh = (const float*)d_in[9];
    const float* lw1 = (const float*)d_in[10];
    const float* lb1 = (const float*)d_in[11];
    const float* lw2 = (const float*)d_in[12];
    const float* lb2 = (const float*)d_in[13];
    unsigned short* wsb = (unsigned short*)d_ws;

    prep_weights<<<176, 256, 0, stream>>>(w1, w2, wih, whh, lw1, wsb);
    tgn_kernel<<<BATCH / 64, 256, 0, stream>>>(pairs, memory, wsb, b1, b2, bih, bhh,
                                               lb1, lw2, lb2, (float*)d_out);
}

// Round 8
// 183.279 us; speedup vs baseline: 1.2865x; 1.0422x over previous
//
#include <hip/hip_runtime.h>

#define BATCH 262144

typedef __attribute__((ext_vector_type(8))) short short8;
typedef __attribute__((ext_vector_type(4))) float f32x4;

static __device__ __forceinline__ unsigned cvtpk(float lo, float hi) {
    unsigned r;
    asm("v_cvt_pk_bf16_f32 %0, %1, %2" : "=v"(r) : "v"(lo), "v"(hi));
    return r;
}
// float -> bf16 bits (RNE) for the weight-prep kernel
static __device__ __forceinline__ unsigned short f2b(float f) {
    unsigned u = __float_as_uint(f);
    return (unsigned short)((u + 0x7fffu + ((u >> 16) & 1u)) >> 16);
}
static __device__ __forceinline__ float b2f(short s) {
    return __uint_as_float(((unsigned)(unsigned short)s) << 16);
}
static __device__ __forceinline__ float sigm(float x) { return 1.0f / (1.0f + __expf(-x)); }
static __device__ __forceinline__ float tanh_f(float x) { return 1.0f - 2.0f / (__expf(2.0f * x) + 1.0f); }

// LDS buffers are PER-WAVE (no cross-wave sharing). lgkmcnt(0) gives intra-wave
// LDS ordering; the raw s_barrier only phase-locks the 4 waves of the block so
// they stream the same I$/L1D regions together. No vmcnt drain (unlike
// __syncthreads) -> cross-stage global weight prefetch stays alive.
#define STAGE_SYNC() do { \
    asm volatile("s_waitcnt lgkmcnt(0)" ::: "memory"); \
    __builtin_amdgcn_s_barrier(); \
} while (0)

// bf16 weights in workspace: [0:8192) w1, [8192:12288) w2, [12288:24576) w_ih,
//                            [24576:36864) w_hh, [36864:45056) lp_w1
__global__ void prep_weights(const float* __restrict__ w1, const float* __restrict__ w2,
                             const float* __restrict__ wih, const float* __restrict__ whh,
                             const float* __restrict__ lw1, unsigned short* __restrict__ wsb) {
    int i = blockIdx.x * 256 + threadIdx.x;
    float v;
    if (i < 8192) v = w1[i];
    else if (i < 12288) v = w2[i - 8192];
    else if (i < 24576) v = wih[i - 12288];
    else if (i < 36864) v = whh[i - 24576];
    else if (i < 45056) v = lw1[i - 36864];
    else return;
    wsb[i] = f2b(v);
}

#define LDB 72    // bf16 LDS row stride: 144 B rows (16B-aligned rows)
#define LDC 136   // comb row stride: 272 B rows

// (256,4): 128 regs/wave incl. AGPR — R4/R6 proved lower spills, R5 proved
// higher halves occupancy for no gain.
__global__ __launch_bounds__(256, 4) void tgn_kernel(
    const int* __restrict__ pairs, const float* __restrict__ memory,
    const unsigned short* __restrict__ wsb,
    const float* __restrict__ b1, const float* __restrict__ b2,
    const float* __restrict__ bih, const float* __restrict__ bhh,
    const float* __restrict__ lb1, const float* __restrict__ lw2,
    const float* __restrict__ lb2, float* __restrict__ out)
{
    __shared__ __align__(16) short nmem[4][2][16 * LDB];  // 18432 B: n1/n2 bf16
    __shared__ __align__(16) short scr[4][2304];          // 18432 B: h1b@0, msgb@1152; comb overlays

    const int tid = threadIdx.x;
    const int w  = tid >> 6;
    const int l  = tid & 63;
    const int lr = l & 15;       // M/N index within fragment
    const int lg = l >> 4;       // k-group / row-group

    const int r0 = (blockIdx.x * 4 + w) * 16;

    short* n1b  = &nmem[w][0][0];
    short* n2b  = &nmem[w][1][0];
    short* h1b  = &scr[w][0];
    short* msgb = &scr[w][1152];
    short* comb = &scr[w][0];

    const unsigned short* w1b  = wsb;          // [64][128]
    const unsigned short* w2b  = wsb + 8192;   // [64][64]
    const unsigned short* wihb = wsb + 12288;  // [192][64]
    const unsigned short* whhb = wsb + 24576;  // [192][64]
    const unsigned short* lw1b = wsb + 36864;  // [64][128]

    const f32x4 z4 = {0.0f, 0.0f, 0.0f, 0.0f};

    // ---- stage 0: coalesced gather -> bf16 LDS. 16 lanes fetch one 256B row ----
    // (R7's per-lane-owns-row gather scattered each instruction over 16 rows;
    //  this form makes each dwordx4 a 4x256B coalesced access.)
#pragma unroll
    for (int rr = 0; rr < 4; ++rr) {
        int row = rr * 4 + lg;
        long i1 = pairs[(r0 + row) * 2 + 0];
        long i2 = pairs[(r0 + row) * 2 + 1];
        f32x4 v1 = *(const f32x4*)(memory + i1 * 64 + lr * 4);
        f32x4 v2 = *(const f32x4*)(memory + i2 * 64 + lr * 4);
        uint2 c1, c2;
        c1.x = cvtpk(v1[0], v1[1]); c1.y = cvtpk(v1[2], v1[3]);
        c2.x = cvtpk(v2[0], v2[1]); c2.y = cvtpk(v2[2], v2[3]);
        *(uint2*)(n1b + row * LDB + lr * 4) = c1;
        *(uint2*)(n2b + row * LDB + lr * 4) = c2;
    }
    STAGE_SYNC();

    // ---- stage 1: H1 = relu(X @ w1^T + b1), X = [n1|n2] (16x128) ----
    f32x4 acc[4];
#pragma unroll
    for (int nt = 0; nt < 4; ++nt) acc[nt] = z4;
#pragma unroll
    for (int kt = 0; kt < 4; ++kt) {
        const short* ap = (kt < 2 ? n1b : n2b) + lr * LDB + (kt & 1) * 32 + lg * 8;
        short8 a = *(const short8*)ap;
#pragma unroll
        for (int nt = 0; nt < 4; ++nt) {
            short8 b = *(const short8*)(w1b + (nt * 16 + lr) * 128 + kt * 32 + lg * 8);
            acc[nt] = __builtin_amdgcn_mfma_f32_16x16x32_bf16(a, b, acc[nt], 0, 0, 0);
        }
    }
#pragma unroll
    for (int nt = 0; nt < 4; ++nt) {
        float bv = b1[nt * 16 + lr];
        unsigned p01 = cvtpk(fmaxf(acc[nt][0] + bv, 0.0f), fmaxf(acc[nt][1] + bv, 0.0f));
        unsigned p23 = cvtpk(fmaxf(acc[nt][2] + bv, 0.0f), fmaxf(acc[nt][3] + bv, 0.0f));
        int cb = nt * 16 + lr;
        h1b[(lg * 4 + 0) * LDB + cb] = (short)p01;
        h1b[(lg * 4 + 1) * LDB + cb] = (short)(p01 >> 16);
        h1b[(lg * 4 + 2) * LDB + cb] = (short)p23;
        h1b[(lg * 4 + 3) * LDB + cb] = (short)(p23 >> 16);
    }
    STAGE_SYNC();

    // ---- stage 2: MSG = H1 @ w2^T + b2 (16x64) ----
#pragma unroll
    for (int nt = 0; nt < 4; ++nt) acc[nt] = z4;
#pragma unroll
    for (int kt = 0; kt < 2; ++kt) {
        short8 a = *(const short8*)(h1b + lr * LDB + kt * 32 + lg * 8);
#pragma unroll
        for (int nt = 0; nt < 4; ++nt) {
            short8 b = *(const short8*)(w2b + (nt * 16 + lr) * 64 + kt * 32 + lg * 8);
            acc[nt] = __builtin_amdgcn_mfma_f32_16x16x32_bf16(a, b, acc[nt], 0, 0, 0);
        }
    }
#pragma unroll
    for (int nt = 0; nt < 4; ++nt) {
        float bv = b2[nt * 16 + lr];
        unsigned p01 = cvtpk(acc[nt][0] + bv, acc[nt][1] + bv);
        unsigned p23 = cvtpk(acc[nt][2] + bv, acc[nt][3] + bv);
        int cb = nt * 16 + lr;
        msgb[(lg * 4 + 0) * LDB + cb] = (short)p01;
        msgb[(lg * 4 + 1) * LDB + cb] = (short)(p01 >> 16);
        msgb[(lg * 4 + 2) * LDB + cb] = (short)p23;
        msgb[(lg * 4 + 3) * LDB + cb] = (short)(p23 >> 16);
    }
    STAGE_SYNC();

    // ---- stage 3+4 fused: per column-block nt, 9 gate tiles then GRU ----
    short8 am[2], a1[2], a2[2];
#pragma unroll
    for (int kt = 0; kt < 2; ++kt) {
        am[kt] = *(const short8*)(msgb + lr * LDB + kt * 32 + lg * 8);
        a1[kt] = *(const short8*)(n1b + lr * LDB + kt * 32 + lg * 8);
        a2[kt] = *(const short8*)(n2b + lr * LDB + kt * 32 + lg * 8);
    }
#pragma unroll
    for (int nt = 0; nt < 4; ++nt) {
        f32x4 gir = z4, giz = z4, gin = z4;
        f32x4 g1r = z4, g1z = z4, g1n = z4;
        f32x4 g2r = z4, g2z = z4, g2n = z4;
#pragma unroll
        for (int kt = 0; kt < 2; ++kt) {
            int ko = kt * 32 + lg * 8;
            short8 bir = *(const short8*)(wihb + ((0 + nt) * 16 + lr) * 64 + ko);
            short8 biz = *(const short8*)(wihb + ((4 + nt) * 16 + lr) * 64 + ko);
            short8 bin = *(const short8*)(wihb + ((8 + nt) * 16 + lr) * 64 + ko);
            short8 bhr = *(const short8*)(whhb + ((0 + nt) * 16 + lr) * 64 + ko);
            short8 bhz = *(const short8*)(whhb + ((4 + nt) * 16 + lr) * 64 + ko);
            short8 bhn = *(const short8*)(whhb + ((8 + nt) * 16 + lr) * 64 + ko);
            gir = __builtin_amdgcn_mfma_f32_16x16x32_bf16(am[kt], bir, gir, 0, 0, 0);
            giz = __builtin_amdgcn_mfma_f32_16x16x32_bf16(am[kt], biz, giz, 0, 0, 0);
            gin = __builtin_amdgcn_mfma_f32_16x16x32_bf16(am[kt], bin, gin, 0, 0, 0);
            g1r = __builtin_amdgcn_mfma_f32_16x16x32_bf16(a1[kt], bhr, g1r, 0, 0, 0);
            g1z = __builtin_amdgcn_mfma_f32_16x16x32_bf16(a1[kt], bhz, g1z, 0, 0, 0);
            g1n = __builtin_amdgcn_mfma_f32_16x16x32_bf16(a1[kt], bhn, g1n, 0, 0, 0);
            g2r = __builtin_amdgcn_mfma_f32_16x16x32_bf16(a2[kt], bhr, g2r, 0, 0, 0);
            g2z = __builtin_amdgcn_mfma_f32_16x16x32_bf16(a2[kt], bhz, g2z, 0, 0, 0);
            g2n = __builtin_amdgcn_mfma_f32_16x16x32_bf16(a2[kt], bhn, g2n, 0, 0, 0);
        }
        int j = nt * 16 + lr;
        float bir_ = bih[j], biz_ = bih[64 + j], bin_ = bih[128 + j];
        float bhr_ = bhh[j], bhz_ = bhh[64 + j], bhn_ = bhh[128 + j];
        float o1[4], o2[4];
#pragma unroll
        for (int r = 0; r < 4; ++r) {
            int row = lg * 4 + r;
            float i_r = gir[r] + bir_;
            float i_z = giz[r] + biz_;
            float i_n = gin[r] + bin_;
            // node 1 (h from LDS bf16 copy — no global re-read)
            float rg = sigm(i_r + g1r[r] + bhr_);
            float zg = sigm(i_z + g1z[r] + bhz_);
            float ng = tanh_f(i_n + rg * (g1n[r] + bhn_));
            float h  = b2f(n1b[row * LDB + j]);
            o1[r] = (1.0f - zg) * ng + zg * h;
            // node 2
            rg = sigm(i_r + g2r[r] + bhr_);
            zg = sigm(i_z + g2z[r] + bhz_);
            ng = tanh_f(i_n + rg * (g2n[r] + bhn_));
            h  = b2f(n2b[row * LDB + j]);
            o2[r] = (1.0f - zg) * ng + zg * h;
        }
        unsigned q01 = cvtpk(o1[0], o1[1]), q23 = cvtpk(o1[2], o1[3]);
        unsigned s01 = cvtpk(o2[0], o2[1]), s23 = cvtpk(o2[2], o2[3]);
        comb[(lg * 4 + 0) * LDC + j] = (short)q01;
        comb[(lg * 4 + 1) * LDC + j] = (short)(q01 >> 16);
        comb[(lg * 4 + 2) * LDC + j] = (short)q23;
        comb[(lg * 4 + 3) * LDC + j] = (short)(q23 >> 16);
        comb[(lg * 4 + 0) * LDC + 64 + j] = (short)s01;
        comb[(lg * 4 + 1) * LDC + 64 + j] = (short)(s01 >> 16);
        comb[(lg * 4 + 2) * LDC + 64 + j] = (short)s23;
        comb[(lg * 4 + 3) * LDC + 64 + j] = (short)(s23 >> 16);
    }
    STAGE_SYNC();

    // ---- stage 5: H = relu(COMB @ lp_w1^T + lb1) (16x64) ----
    f32x4 acc5[4];
#pragma unroll
    for (int nt = 0; nt < 4; ++nt) acc5[nt] = z4;
#pragma unroll
    for (int kt = 0; kt < 4; ++kt) {
        short8 a = *(const short8*)(comb + lr * LDC + kt * 32 + lg * 8);
#pragma unroll
        for (int nt = 0; nt < 4; ++nt) {
            short8 b = *(const short8*)(lw1b + (nt * 16 + lr) * 128 + kt * 32 + lg * 8);
            acc5[nt] = __builtin_amdgcn_mfma_f32_16x16x32_bf16(a, b, acc5[nt], 0, 0, 0);
        }
    }

    // ---- stage 6: out = sigmoid(H @ lp_w2^T + lb2), reduce over 64 cols ----
    float part[4] = {0.0f, 0.0f, 0.0f, 0.0f};
#pragma unroll
    for (int nt = 0; nt < 4; ++nt) {
        float w2v = lw2[nt * 16 + lr];
        float bv  = lb1[nt * 16 + lr];
#pragma unroll
        for (int r = 0; r < 4; ++r)
            part[r] += fmaxf(acc5[nt][r] + bv, 0.0f) * w2v;
    }
    float lb2v = lb2[0];
#pragma unroll
    for (int r = 0; r < 4; ++r) {
        float p = part[r];
        p += __shfl_xor(p, 1);
        p += __shfl_xor(p, 2);
        p += __shfl_xor(p, 4);
        p += __shfl_xor(p, 8);
        if (lr == 0) out[r0 + lg * 4 + r] = sigm(p + lb2v);
    }
}

extern "C" void kernel_launch(void* const* d_in, const int* in_sizes, int n_in,
                              void* d_out, int out_size, void* d_ws, size_t ws_size,
                              hipStream_t stream) {
    const int*   pairs  = (const int*)d_in[0];
    const float* memory = (const float*)d_in[1];
    const float* w1  = (const float*)d_in[2];
    const float* b1  = (const float*)d_in[3];
    const float* w2  = (const float*)d_in[4];
    const float* b2  = (const float*)d_in[5];
    const float* wih = (const float*)d_in[6];
    const float* whh = (const float*)d_in[7];
    const float* bih = (const float*)d_in[8];
    const float* bhh = (const float*)d_in[9];
    const float* lw1 = (const float*)d_in[10];
    const float* lb1 = (const float*)d_in[11];
    const float* lw2 = (const float*)d_in[12];
    const float* lb2 = (const float*)d_in[13];
    unsigned short* wsb = (unsigned short*)d_ws;

    prep_weights<<<176, 256, 0, stream>>>(w1, w2, wih, whh, lw1, wsb);
    tgn_kernel<<<BATCH / 64, 256, 0, stream>>>(pairs, memory, wsb, b1, b2, bih, bhh,
                                               lb1, lw2, lb2, (float*)d_out);
}